// Round 1
// 391.051 us; speedup vs baseline: 1.1227x; 1.1227x over previous
//
#include <hip/hip_runtime.h>
#include <hip/hip_bf16.h>

#define NB 64     // batch
#define NI 2048   // input capsules
#define ND 16     // d_in
#define NJ 32     // output capsules
#define NE 32     // d_out
#define NIP (NI/2)  // i-pairs
#define NKC 32    // wsum grid kc dimension (32 ip-chunks)
#define NSL NKC   // one partial slice per wsum block (cross-wave LDS reduce)

typedef __attribute__((ext_vector_type(8))) short bfrag;   // 8 bf16 (4 VGPRs)
typedef __attribute__((ext_vector_type(4))) float f32x4;

// two floats -> packed bf16x2 (v_cvt_pk_bf16_f32 on gfx950), RNE
__device__ inline unsigned pk2bf(float a, float b) {
    __hip_bfloat162 h = __float22bfloat162_rn(make_float2(a, b));
    return *reinterpret_cast<unsigned*>(&h);
}

// add value rotated by N within each 16-lane DPP row (row_ror:N)
template <int N>
__device__ inline float rot16_add(float v) {
    int r = __builtin_amdgcn_mov_dpp(__float_as_int(v), 0x120 + N, 0xf, 0xf, false);
    return v + __int_as_float(r);
}

// unpack a dword of 2 bf16, scale by cc, repack (RNE)
__device__ inline unsigned scale_pair(unsigned u, float cc) {
    float f0 = __uint_as_float(u << 16);
    float f1 = __uint_as_float(u & 0xffff0000u);
    return pk2bf(f0 * cc, f1 * cc);
}

// ---------------------------------------------------------------------------
// convxT_k: x fp32 [NB][NI][ND] -> xT bf16 [NI][NB][ND].
// b fastest across lanes -> coalesced writes; reads touch each line once.
// ---------------------------------------------------------------------------
__global__ __launch_bounds__(256) void convxT_k(const float* __restrict__ x,
                                                short* __restrict__ xT)
{
    const int T = blockIdx.x * 256 + threadIdx.x;   // NI*NB = 131072
    const int i = T >> 6, b = T & 63;
    const float4* src = reinterpret_cast<const float4*>(
        x + ((size_t)b * NI + i) * ND);
    float4 a0 = src[0], a1 = src[1], a2 = src[2], a3 = src[3];
    bfrag lo, hi;
    unsigned* lu = reinterpret_cast<unsigned*>(&lo);
    unsigned* hu = reinterpret_cast<unsigned*>(&hi);
    lu[0] = pk2bf(a0.x, a0.y); lu[1] = pk2bf(a0.z, a0.w);
    lu[2] = pk2bf(a1.x, a1.y); lu[3] = pk2bf(a1.z, a1.w);
    hu[0] = pk2bf(a2.x, a2.y); hu[1] = pk2bf(a2.z, a2.w);
    hu[2] = pk2bf(a3.x, a3.y); hu[3] = pk2bf(a3.z, a3.w);
    short* dst = xT + ((size_t)i * NB + b) * ND;
    *reinterpret_cast<bfrag*>(dst)     = lo;
    *reinterpret_cast<bfrag*>(dst + 8) = hi;
}

// ---------------------------------------------------------------------------
// lgsm_k: fused logits + softmax. Block = 16 b x 16 i x ALL 32 j (8 waves,
// 4 j each). Logits via K=16-padded mfma + DPP e-reduction into 32KB LDS,
// one barrier, softmax over j, write c[j][i][b]. A-frags: single 16B loads
// from xT (wave-contiguous).
// Grid: flat 512 with XCD co-location swizzle: the 4 bb-blocks that share
// one 512KB Wb slice (same ic) get the same (blockIdx%8) -> same XCD L2.
//   l = grp*32 + bb*8 + x ;  ic = grp*8 + x  (bijective, sharers = same x)
// ---------------------------------------------------------------------------
__global__ __launch_bounds__(512) void lgsm_k(
    const short* __restrict__ xT,     // [NI][NB][ND] bf16
    const short* __restrict__ Wb,     // [NJ][NIP][NE][32] bf16
    const float* __restrict__ Oacc,   // [NB][NJ][NE]
    float* __restrict__ c)            // [NJ][NI][NB]
{
    const int l    = blockIdx.x;       // 0..511
    const int grp  = l >> 5;           // 16 groups
    const int bb   = (l >> 3) & 3;
    const int ic   = grp * 8 + (l & 7);
    const int b0   = bb * 16;
    const int i0   = ic * 16;
    const int t    = threadIdx.x;
    const int wv   = t >> 6;           // 0..7 -> j-set wv*4..wv*4+3
    const int ln   = t & 63;
    const int m    = ln & 15;
    const int quad = ln >> 4;

    __shared__ float lp[NJ][16][16];   // [j][i][b] 32 KB

    // Hoist Oacc fragments for this wave's 4 j's.
    float O0[4][4], O1[4][4];
#pragma unroll
    for (int jj = 0; jj < 4; ++jj) {
        const int j = wv * 4 + jj;
#pragma unroll
        for (int r = 0; r < 4; ++r) {
            const int b = b0 + quad * 4 + r;
            O0[jj][r] = Oacc[((size_t)b * NJ + j) * NE + m];
            O1[jj][r] = Oacc[((size_t)b * NJ + j) * NE + 16 + m];
        }
    }

    const int  bA  = b0 + m;        // A-operand row (b) this lane supplies
    const bool act = quad < 2;      // quads 0,1 carry k=0..15 (d); 2,3 zero pad
    const int  d0  = quad * 8;

    for (int il = 0; il < 16; ++il) {
        const int i = i0 + il;
        const int ip = i >> 1, isel = i & 1;
        bfrag av = (bfrag)0;
        if (act) {
            av = *reinterpret_cast<const bfrag*>(
                xT + ((size_t)i * NB + bA) * ND + d0);
        }
#pragma unroll
        for (int jj = 0; jj < 4; ++jj) {
            const int j = wv * 4 + jj;
            bfrag bv0 = (bfrag)0, bv1 = (bfrag)0;
            if (act) {
                const short* wp = Wb + (((size_t)j * NIP + ip) * NE + m) * 32
                                     + isel * 16 + d0;
                bv0 = *reinterpret_cast<const bfrag*>(wp);
                bv1 = *reinterpret_cast<const bfrag*>(wp + 16 * 32);
            }
            f32x4 z = {0.f, 0.f, 0.f, 0.f};
            f32x4 U0 = __builtin_amdgcn_mfma_f32_16x16x32_bf16(av, bv0, z, 0, 0, 0);
            f32x4 U1 = __builtin_amdgcn_mfma_f32_16x16x32_bf16(av, bv1, z, 0, 0, 0);

            float v4[4];
#pragma unroll
            for (int r = 0; r < 4; ++r) {
                float v = fmaf(U0[r], O0[jj][r], U1[r] * O1[jj][r]);
                v = rot16_add<1>(v);
                v = rot16_add<2>(v);
                v = rot16_add<4>(v);
                v = rot16_add<8>(v);
                v4[r] = v;
            }
            if (m == 0) {
                *reinterpret_cast<float4*>(&lp[j][il][quad * 4]) =
                    make_float4(v4[0], v4[1], v4[2], v4[3]);
            }
        }
    }
    __syncthreads();

    // softmax over j: threads 0..255 each own one (i,b) row.
    if (t < 256) {
        const int i = t >> 4, b = t & 15;
        float v[NJ];
        float mx = -1e30f;
#pragma unroll
        for (int jx = 0; jx < NJ; ++jx) {
            v[jx] = lp[jx][i][b];
            mx = fmaxf(mx, v[jx]);
        }
        float sum = 0.f;
#pragma unroll
        for (int jx = 0; jx < NJ; ++jx) {
            v[jx] = __expf(v[jx] - mx);
            sum += v[jx];
        }
        const float inv = 1.0f / sum;
#pragma unroll
        for (int jx = 0; jx < NJ; ++jx)
            c[((size_t)jx * NI + i0 + i) * NB + b0 + b] = v[jx] * inv;
    }
}

// ---------------------------------------------------------------------------
// wsum_k: split-K partials of s[b,j,e] = sum_i c[j,i,b] * u_hat[b,j,i,e].
// Block = 256 threads = 4 waves; each wave owns 8 i-pairs and all 4 M-tiles
// (64 b). Per-wave inner loop identical to the proven 2-wave version.
// New: (a) R0 variant reads W fp32 directly, converts to bf16 fragments
// in-register (v_cvt_pk_bf16_f32) and stores Wb as a byproduct -> the
// separate convw pass and its 67MB Wb re-read are gone.
// (b) the 4 waves' accumulators are reduced through 32KB LDS and ONE slice
// is written per block: NSL 128 -> 32, partial round-trip 64 -> 16 MB/round.
// grid (j=32, kc=32), block 256.
// ---------------------------------------------------------------------------
template <bool R0>
__global__ __launch_bounds__(256, 4) void wsum_k(
    const float* __restrict__ Wsrc,   // [NJ][NI][NE][ND] fp32 (used iff R0)
    const short* __restrict__ xT,     // [NI][NB][ND] bf16
    short* __restrict__ Wb,           // [NJ][NIP][NE][32] bf16 (W iff R0, R else)
    const float* __restrict__ c,      // [NJ][NI][NB] (unused if R0)
    float* __restrict__ partial)      // [NSL][NJ][2048]
{
    const int j    = blockIdx.x;
    const int kc   = blockIdx.y;
    const int t    = threadIdx.x;
    const int wv   = t >> 6;
    const int ln   = t & 63;
    const int m    = ln & 15;
    const int quad = ln >> 4;
    const int isel = quad >> 1;        // which of the 2 i's in the K-chunk
    const int d0   = (quad & 1) * 8;   // which 8 d's (element offset)
    const int ip0  = kc * 32 + wv * 8; // this wave's 8 i-pairs

    __shared__ float red[4][2048];     // 32 KB cross-wave reduction buffer

    f32x4 acc[4][2];
#pragma unroll
    for (int a = 0; a < 4; ++a)
#pragma unroll
        for (int n = 0; n < 2; ++n) acc[a][n] = (f32x4){0.f, 0.f, 0.f, 0.f};

#pragma unroll 2
    for (int it = 0; it < 8; ++it) {
        const int ip = ip0 + it;
        const int ia = ip * 2 + isel;
        bfrag bv0, bv1;
        if (R0) {
            // read W fp32 (4KB/wave contiguous), convert, store Wb byproduct
            const float* wp0 = Wsrc + (((size_t)j * NI + ia) * NE + m) * ND + d0;
            float4 w0 = *reinterpret_cast<const float4*>(wp0);
            float4 w1 = *reinterpret_cast<const float4*>(wp0 + 4);
            float4 w2 = *reinterpret_cast<const float4*>(wp0 + 16 * ND);
            float4 w3 = *reinterpret_cast<const float4*>(wp0 + 16 * ND + 4);
            unsigned* b0u = reinterpret_cast<unsigned*>(&bv0);
            unsigned* b1u = reinterpret_cast<unsigned*>(&bv1);
            b0u[0] = pk2bf(w0.x, w0.y); b0u[1] = pk2bf(w0.z, w0.w);
            b0u[2] = pk2bf(w1.x, w1.y); b0u[3] = pk2bf(w1.z, w1.w);
            b1u[0] = pk2bf(w2.x, w2.y); b1u[1] = pk2bf(w2.z, w2.w);
            b1u[2] = pk2bf(w3.x, w3.y); b1u[3] = pk2bf(w3.z, w3.w);
            short* wd = Wb + (((size_t)j * NIP + ip) * NE + m) * 32 + quad * 8;
            *reinterpret_cast<bfrag*>(wd)       = bv0;   // k = quad*8..+7
            *reinterpret_cast<bfrag*>(wd + 512) = bv1;   // e+16 row
        } else {
            const short* wp = Wb + (((size_t)j * NIP + ip) * NE + m) * 32 + quad * 8;
            bv0 = *reinterpret_cast<const bfrag*>(wp);
            bv1 = *reinterpret_cast<const bfrag*>(wp + 512);
        }
#pragma unroll
        for (int mt = 0; mt < 4; ++mt) {
            const int b = mt * 16 + m;
            const float cc = R0 ? (1.0f / NJ)
                                : c[((size_t)j * NI + ia) * NB + b];
            const uint4 xr = *reinterpret_cast<const uint4*>(
                xT + ((size_t)ia * NB + b) * ND + d0);
            bfrag av;
            unsigned* avu = reinterpret_cast<unsigned*>(&av);
            avu[0] = scale_pair(xr.x, cc);
            avu[1] = scale_pair(xr.y, cc);
            avu[2] = scale_pair(xr.z, cc);
            avu[3] = scale_pair(xr.w, cc);
            acc[mt][0] = __builtin_amdgcn_mfma_f32_16x16x32_bf16(av, bv0, acc[mt][0], 0, 0, 0);
            acc[mt][1] = __builtin_amdgcn_mfma_f32_16x16x32_bf16(av, bv1, acc[mt][1], 0, 0, 0);
        }
    }

    // stage per-wave accumulators in the SAME flat layout rs_k decodes
    float* rb = &red[wv][0];
#pragma unroll
    for (int mt = 0; mt < 4; ++mt)
#pragma unroll
        for (int nt = 0; nt < 2; ++nt)
            *reinterpret_cast<f32x4*>(rb + (mt * 2 + nt) * 256 + ln * 4)
                = acc[mt][nt];
    __syncthreads();

    // cooperative 4-wave sum: 256 threads x 2 f32x4 (contiguous, conflict-free)
    float* pb = partial + ((size_t)kc * NJ + j) * 2048;
    {
        const int g = t * 4;
        f32x4 s0 = *reinterpret_cast<const f32x4*>(&red[0][g]);
        s0 += *reinterpret_cast<const f32x4*>(&red[1][g]);
        s0 += *reinterpret_cast<const f32x4*>(&red[2][g]);
        s0 += *reinterpret_cast<const f32x4*>(&red[3][g]);
        f32x4 s1 = *reinterpret_cast<const f32x4*>(&red[0][1024 + g]);
        s1 += *reinterpret_cast<const f32x4*>(&red[1][1024 + g]);
        s1 += *reinterpret_cast<const f32x4*>(&red[2][1024 + g]);
        s1 += *reinterpret_cast<const f32x4*>(&red[3][1024 + g]);
        *reinterpret_cast<f32x4*>(pb + g)        = s0;
        *reinterpret_cast<f32x4*>(pb + 1024 + g) = s1;
    }
}

// ---------------------------------------------------------------------------
// rs_k: fused reduce (sum over NSL slices) + squash + state update.
// Block = 512 threads = one (j, mt) pair = 16 b x 32 e -> LDS row-norm.
// mode 0: Oacc = squash(s); mode 1: Oacc += squash(s); mode 2: out = squash(s).
// ---------------------------------------------------------------------------
__global__ __launch_bounds__(512) void rs_k(
    const float* __restrict__ partial,   // [NSL][NJ][2048]
    float* __restrict__ Oacc,            // [NB][NJ][NE]
    float* __restrict__ out,             // [NB][NJ][NE]
    int mode)
{
    const int G    = blockIdx.x * 512 + threadIdx.x;   // 0..65535
    const int j    = G >> 11;
    const int g    = G & 2047;
    const int group = g >> 8;           // 0..7 = mt*2+nt
    const int mt   = group >> 1;
    const int nt   = group & 1;
    const int lnn  = (g >> 2) & 63;
    const int m    = lnn & 15;
    const int quad = lnn >> 4;
    const int r    = g & 3;
    const int b    = mt * 16 + quad * 4 + r;
    const int e    = nt * 16 + m;

    float sum = 0.f;
#pragma unroll 8
    for (int sl = 0; sl < NSL; ++sl)
        sum += partial[((size_t)sl * NJ + j) * 2048 + g];

    // LDS norm: 16 b-rows x 32 e per block (mt fixed within block).
    __shared__ float lds[512];
    const int row = quad * 4 + r;        // 0..15
    lds[row * 32 + e] = sum;
    __syncthreads();
    const float* rp = &lds[row * 32];
    float p = 0.f;
#pragma unroll
    for (int ee = 0; ee < 32; ++ee) p = fmaf(rp[ee], rp[ee], p);

    const float scale = p / ((1.0f + p) * sqrtf(p + 1e-7f));
    const float o = scale * sum;
    const size_t off = ((size_t)b * NJ + j) * NE + e;
    if (mode == 2)      out[off]  = o;
    else if (mode == 1) Oacc[off] += o;
    else                Oacc[off] = o;
}

extern "C" void kernel_launch(void* const* d_in, const int* in_sizes, int n_in,
                              void* d_out, int out_size, void* d_ws, size_t ws_size,
                              hipStream_t stream)
{
    (void)in_sizes; (void)n_in; (void)out_size; (void)ws_size;
    const float* x = (const float*)d_in[0];   // [64][2048][16]
    const float* W = (const float*)d_in[1];   // [32][2048][32][16]
    float* out = (float*)d_out;               // [64][32][32]

    // ws layout (~96 MB of 512 MB). Every buffer fully written before read.
    float* Oacc = (float*)d_ws;                        // 64K floats  (256 KB)
    float* c    = Oacc + NB * NJ * NE;                 // [NJ][NI][NB] (16 MB)
    float* part = c + (size_t)NJ * NI * NB;            // [NSL][NJ][2048] (8 MB)
    short* Wb   = (short*)(part + (size_t)NSL * NJ * 2048);  // 32M bf16 (64 MB)
    short* xT   = Wb + (size_t)NJ * NIP * NE * 32;           // 4M bf16  (8 MB)

    // pre-convert: x -> xT (transposed bf16). W conversion is fused into
    // the round-0 wsum (reads W fp32 once, emits Wb as a byproduct).
    convxT_k<<<(NI * NB) / 256, 256, 0, stream>>>(x, xT);

    dim3 gW(NJ, NKC);          // wsum grid (32, 32), 256-thread blocks

    // round 0: uniform c = 1/32; converts W -> Wb inline
    wsum_k<true><<<gW, 256, 0, stream>>>(W, xT, Wb, c, part);
    rs_k<<<65536 / 512, 512, 0, stream>>>(part, Oacc, out, 0);

    // round 1
    lgsm_k<<<512, 512, 0, stream>>>(xT, Wb, Oacc, c);
    wsum_k<false><<<gW, 256, 0, stream>>>(W, xT, Wb, c, part);
    rs_k<<<65536 / 512, 512, 0, stream>>>(part, Oacc, out, 1);

    // round 2
    lgsm_k<<<512, 512, 0, stream>>>(xT, Wb, Oacc, c);
    wsum_k<false><<<gW, 256, 0, stream>>>(W, xT, Wb, c, part);
    rs_k<<<65536 / 512, 512, 0, stream>>>(part, Oacc, out, 2);
}

// Round 2
// 381.869 us; speedup vs baseline: 1.1497x; 1.0240x over previous
//
#include <hip/hip_runtime.h>
#include <hip/hip_bf16.h>

#define NB 64     // batch
#define NI 2048   // input capsules
#define ND 16     // d_in
#define NJ 32     // output capsules
#define NE 32     // d_out
#define NIP (NI/2)  // i-pairs
#define NKC 64    // wsum grid kc dimension (64 chunks of 16 ip)
#define NSL NKC   // one partial slice per wsum block (2-wave LDS reduce)

typedef __attribute__((ext_vector_type(8))) short bfrag;   // 8 bf16 (4 VGPRs)
typedef __attribute__((ext_vector_type(4))) float f32x4;

// two floats -> packed bf16x2 (v_cvt_pk_bf16_f32 on gfx950), RNE
__device__ inline unsigned pk2bf(float a, float b) {
    __hip_bfloat162 h = __float22bfloat162_rn(make_float2(a, b));
    return *reinterpret_cast<unsigned*>(&h);
}

// add value rotated by N within each 16-lane DPP row (row_ror:N)
template <int N>
__device__ inline float rot16_add(float v) {
    int r = __builtin_amdgcn_mov_dpp(__float_as_int(v), 0x120 + N, 0xf, 0xf, false);
    return v + __int_as_float(r);
}

// unpack a dword of 2 bf16, scale by cc, repack (RNE)
__device__ inline unsigned scale_pair(unsigned u, float cc) {
    float f0 = __uint_as_float(u << 16);
    float f1 = __uint_as_float(u & 0xffff0000u);
    return pk2bf(f0 * cc, f1 * cc);
}

// ---------------------------------------------------------------------------
// convxT_k: x fp32 [NB][NI][ND] -> xT bf16 [NI][NB][ND].
// ---------------------------------------------------------------------------
__global__ __launch_bounds__(256) void convxT_k(const float* __restrict__ x,
                                                short* __restrict__ xT)
{
    const int T = blockIdx.x * 256 + threadIdx.x;   // NI*NB = 131072
    const int i = T >> 6, b = T & 63;
    const float4* src = reinterpret_cast<const float4*>(
        x + ((size_t)b * NI + i) * ND);
    float4 a0 = src[0], a1 = src[1], a2 = src[2], a3 = src[3];
    bfrag lo, hi;
    unsigned* lu = reinterpret_cast<unsigned*>(&lo);
    unsigned* hu = reinterpret_cast<unsigned*>(&hi);
    lu[0] = pk2bf(a0.x, a0.y); lu[1] = pk2bf(a0.z, a0.w);
    lu[2] = pk2bf(a1.x, a1.y); lu[3] = pk2bf(a1.z, a1.w);
    hu[0] = pk2bf(a2.x, a2.y); hu[1] = pk2bf(a2.z, a2.w);
    hu[2] = pk2bf(a3.x, a3.y); hu[3] = pk2bf(a3.z, a3.w);
    short* dst = xT + ((size_t)i * NB + b) * ND;
    *reinterpret_cast<bfrag*>(dst)     = lo;
    *reinterpret_cast<bfrag*>(dst + 8) = hi;
}

// ---------------------------------------------------------------------------
// lgsm_k: fused logits + softmax (unchanged, proven). Flat grid 512 with
// XCD co-location swizzle: the 4 bb-blocks sharing a Wb slice (same ic)
// get the same (blockIdx%8) -> same XCD L2.
// ---------------------------------------------------------------------------
__global__ __launch_bounds__(512) void lgsm_k(
    const short* __restrict__ xT,     // [NI][NB][ND] bf16
    const short* __restrict__ Wb,     // [NJ][NIP][NE][32] bf16
    const float* __restrict__ Oacc,   // [NB][NJ][NE]
    float* __restrict__ c)            // [NJ][NI][NB]
{
    const int l    = blockIdx.x;       // 0..511
    const int grp  = l >> 5;           // 16 groups
    const int bb   = (l >> 3) & 3;
    const int ic   = grp * 8 + (l & 7);
    const int b0   = bb * 16;
    const int i0   = ic * 16;
    const int t    = threadIdx.x;
    const int wv   = t >> 6;           // 0..7 -> j-set wv*4..wv*4+3
    const int ln   = t & 63;
    const int m    = ln & 15;
    const int quad = ln >> 4;

    __shared__ float lp[NJ][16][16];   // [j][i][b] 32 KB

    float O0[4][4], O1[4][4];
#pragma unroll
    for (int jj = 0; jj < 4; ++jj) {
        const int j = wv * 4 + jj;
#pragma unroll
        for (int r = 0; r < 4; ++r) {
            const int b = b0 + quad * 4 + r;
            O0[jj][r] = Oacc[((size_t)b * NJ + j) * NE + m];
            O1[jj][r] = Oacc[((size_t)b * NJ + j) * NE + 16 + m];
        }
    }

    const int  bA  = b0 + m;
    const bool act = quad < 2;
    const int  d0  = quad * 8;

    for (int il = 0; il < 16; ++il) {
        const int i = i0 + il;
        const int ip = i >> 1, isel = i & 1;
        bfrag av = (bfrag)0;
        if (act) {
            av = *reinterpret_cast<const bfrag*>(
                xT + ((size_t)i * NB + bA) * ND + d0);
        }
#pragma unroll
        for (int jj = 0; jj < 4; ++jj) {
            const int j = wv * 4 + jj;
            bfrag bv0 = (bfrag)0, bv1 = (bfrag)0;
            if (act) {
                const short* wp = Wb + (((size_t)j * NIP + ip) * NE + m) * 32
                                     + isel * 16 + d0;
                bv0 = *reinterpret_cast<const bfrag*>(wp);
                bv1 = *reinterpret_cast<const bfrag*>(wp + 16 * 32);
            }
            f32x4 z = {0.f, 0.f, 0.f, 0.f};
            f32x4 U0 = __builtin_amdgcn_mfma_f32_16x16x32_bf16(av, bv0, z, 0, 0, 0);
            f32x4 U1 = __builtin_amdgcn_mfma_f32_16x16x32_bf16(av, bv1, z, 0, 0, 0);

            float v4[4];
#pragma unroll
            for (int r = 0; r < 4; ++r) {
                float v = fmaf(U0[r], O0[jj][r], U1[r] * O1[jj][r]);
                v = rot16_add<1>(v);
                v = rot16_add<2>(v);
                v = rot16_add<4>(v);
                v = rot16_add<8>(v);
                v4[r] = v;
            }
            if (m == 0) {
                *reinterpret_cast<float4*>(&lp[j][il][quad * 4]) =
                    make_float4(v4[0], v4[1], v4[2], v4[3]);
            }
        }
    }
    __syncthreads();

    if (t < 256) {
        const int i = t >> 4, b = t & 15;
        float v[NJ];
        float mx = -1e30f;
#pragma unroll
        for (int jx = 0; jx < NJ; ++jx) {
            v[jx] = lp[jx][i][b];
            mx = fmaxf(mx, v[jx]);
        }
        float sum = 0.f;
#pragma unroll
        for (int jx = 0; jx < NJ; ++jx) {
            v[jx] = __expf(v[jx] - mx);
            sum += v[jx];
        }
        const float inv = 1.0f / sum;
#pragma unroll
        for (int jx = 0; jx < NJ; ++jx)
            c[((size_t)jx * NI + i0 + i) * NB + b0 + b] = v[jx] * inv;
    }
}

// ---------------------------------------------------------------------------
// wsum_k: split-K partials of s[b,j,e] = sum_i c[j,i,b] * u_hat[b,j,i,e].
// Round-2 restructure: latency fix. Block = 128 threads (2 waves), grid
// (j=32, kc=64) = 2048 blocks -> 8/CU balance + slack. Per-wave inner math
// is bit-identical to the proven version, but loads go through a MANUAL
// double-buffered prefetch (two NAMED stage structs -> all register-resident,
// no runtime indexing): while stage X computes, stage Y's ~10 wave-loads are
// in flight. This lifts VGPR from 64 (load-serialized) to ~110 and gives the
// memory system real MLP. 2-wave LDS reduce (16 KB) -> one slice per block.
// R0 variant still fuses W fp32 -> Wb bf16 conversion (Wb stored as
// byproduct for rounds 1-2 and lgsm).
// ---------------------------------------------------------------------------
template <bool R0>
__global__ __launch_bounds__(128, 4) void wsum_k(
    const float* __restrict__ Wsrc,   // [NJ][NI][NE][ND] fp32 (used iff R0)
    const short* __restrict__ xT,     // [NI][NB][ND] bf16
    short* __restrict__ Wb,           // [NJ][NIP][NE][32] bf16 (W iff R0, R else)
    const float* __restrict__ c,      // [NJ][NI][NB] (unused if R0)
    float* __restrict__ partial)      // [NSL][NJ][2048]
{
    const int j    = blockIdx.x;
    const int kc   = blockIdx.y;       // 0..63
    const int t    = threadIdx.x;      // 0..127
    const int wv   = t >> 6;           // 0..1
    const int ln   = t & 63;
    const int m    = ln & 15;
    const int quad = ln >> 4;
    const int isel = quad >> 1;        // which of the 2 i's in the K-chunk
    const int d0   = (quad & 1) * 8;   // which 8 d's (element offset)
    const int ip0  = kc * 16 + wv * 8; // this wave's 8 i-pairs

    __shared__ float red[2][2048];     // 16 KB cross-wave reduction buffer

    f32x4 acc[4][2];
#pragma unroll
    for (int a = 0; a < 4; ++a)
#pragma unroll
        for (int n = 0; n < 2; ++n) acc[a][n] = (f32x4){0.f, 0.f, 0.f, 0.f};

    struct Stage {
        bfrag  bv0, bv1;       // non-R0: loaded Wb fragments
        float4 w0, w1, w2, w3; // R0: raw W rows (converted in compute)
        uint4  xr[4];          // xT rows, one per M-tile
        float  cc[4];          // c scalars (non-R0)
    };

    auto load = [&](Stage& S, int it) {
        const int ip = ip0 + it;
        const int ia = ip * 2 + isel;
        if constexpr (R0) {
            const float* wp0 = Wsrc + (((size_t)j * NI + ia) * NE + m) * ND + d0;
            S.w0 = *reinterpret_cast<const float4*>(wp0);
            S.w1 = *reinterpret_cast<const float4*>(wp0 + 4);
            S.w2 = *reinterpret_cast<const float4*>(wp0 + 16 * ND);
            S.w3 = *reinterpret_cast<const float4*>(wp0 + 16 * ND + 4);
        } else {
            const short* wp = Wb + (((size_t)j * NIP + ip) * NE + m) * 32 + quad * 8;
            S.bv0 = *reinterpret_cast<const bfrag*>(wp);
            S.bv1 = *reinterpret_cast<const bfrag*>(wp + 512);
        }
#pragma unroll
        for (int mt = 0; mt < 4; ++mt) {
            const int b = mt * 16 + m;
            if constexpr (!R0)
                S.cc[mt] = c[((size_t)j * NI + ia) * NB + b];
            S.xr[mt] = *reinterpret_cast<const uint4*>(
                xT + ((size_t)ia * NB + b) * ND + d0);
        }
    };

    auto compute = [&](Stage& S, int it) {
        bfrag bv0, bv1;
        if constexpr (R0) {
            unsigned* b0u = reinterpret_cast<unsigned*>(&bv0);
            unsigned* b1u = reinterpret_cast<unsigned*>(&bv1);
            b0u[0] = pk2bf(S.w0.x, S.w0.y); b0u[1] = pk2bf(S.w0.z, S.w0.w);
            b0u[2] = pk2bf(S.w1.x, S.w1.y); b0u[3] = pk2bf(S.w1.z, S.w1.w);
            b1u[0] = pk2bf(S.w2.x, S.w2.y); b1u[1] = pk2bf(S.w2.z, S.w2.w);
            b1u[2] = pk2bf(S.w3.x, S.w3.y); b1u[3] = pk2bf(S.w3.z, S.w3.w);
            const int ip = ip0 + it;
            short* wd = Wb + (((size_t)j * NIP + ip) * NE + m) * 32 + quad * 8;
            *reinterpret_cast<bfrag*>(wd)       = bv0;   // k = quad*8..+7
            *reinterpret_cast<bfrag*>(wd + 512) = bv1;   // e+16 row
        } else {
            bv0 = S.bv0; bv1 = S.bv1;
        }
#pragma unroll
        for (int mt = 0; mt < 4; ++mt) {
            const float cc = R0 ? (1.0f / NJ) : S.cc[mt];
            bfrag av;
            unsigned* avu = reinterpret_cast<unsigned*>(&av);
            avu[0] = scale_pair(S.xr[mt].x, cc);
            avu[1] = scale_pair(S.xr[mt].y, cc);
            avu[2] = scale_pair(S.xr[mt].z, cc);
            avu[3] = scale_pair(S.xr[mt].w, cc);
            acc[mt][0] = __builtin_amdgcn_mfma_f32_16x16x32_bf16(av, bv0, acc[mt][0], 0, 0, 0);
            acc[mt][1] = __builtin_amdgcn_mfma_f32_16x16x32_bf16(av, bv1, acc[mt][1], 0, 0, 0);
        }
    };

    // manual double-buffered pipeline: while one stage computes, the other
    // stage's ~10 wave-loads are in flight. Named stages -> fully in VGPRs.
    Stage sA, sB;
    load(sA, 0);
    load(sB, 1);
#pragma unroll
    for (int it = 0; it < 8; it += 2) {
        compute(sA, it);
        if (it + 2 < 8) load(sA, it + 2);
        compute(sB, it + 1);
        if (it + 3 < 8) load(sB, it + 3);
    }

    // stage per-wave accumulators in the SAME flat layout rs_k decodes
    float* rb = &red[wv][0];
#pragma unroll
    for (int mt = 0; mt < 4; ++mt)
#pragma unroll
        for (int nt = 0; nt < 2; ++nt)
            *reinterpret_cast<f32x4*>(rb + (mt * 2 + nt) * 256 + ln * 4)
                = acc[mt][nt];
    __syncthreads();

    // cooperative 2-wave sum -> one coalesced 8 KB slice per block
    float* pb = partial + ((size_t)kc * NJ + j) * 2048;
#pragma unroll
    for (int k = 0; k < 4; ++k) {
        const int g = k * 512 + t * 4;
        f32x4 s = *reinterpret_cast<const f32x4*>(&red[0][g]);
        s += *reinterpret_cast<const f32x4*>(&red[1][g]);
        *reinterpret_cast<f32x4*>(pb + g) = s;
    }
}

// ---------------------------------------------------------------------------
// rs_k: fused reduce (sum over NSL slices) + squash + state update.
// ---------------------------------------------------------------------------
__global__ __launch_bounds__(512) void rs_k(
    const float* __restrict__ partial,   // [NSL][NJ][2048]
    float* __restrict__ Oacc,            // [NB][NJ][NE]
    float* __restrict__ out,             // [NB][NJ][NE]
    int mode)
{
    const int G    = blockIdx.x * 512 + threadIdx.x;   // 0..65535
    const int j    = G >> 11;
    const int g    = G & 2047;
    const int group = g >> 8;           // 0..7 = mt*2+nt
    const int mt   = group >> 1;
    const int nt   = group & 1;
    const int lnn  = (g >> 2) & 63;
    const int m    = lnn & 15;
    const int quad = lnn >> 4;
    const int r    = g & 3;
    const int b    = mt * 16 + quad * 4 + r;
    const int e    = nt * 16 + m;

    float sum = 0.f;
#pragma unroll 8
    for (int sl = 0; sl < NSL; ++sl)
        sum += partial[((size_t)sl * NJ + j) * 2048 + g];

    __shared__ float lds[512];
    const int row = quad * 4 + r;        // 0..15
    lds[row * 32 + e] = sum;
    __syncthreads();
    const float* rp = &lds[row * 32];
    float p = 0.f;
#pragma unroll
    for (int ee = 0; ee < 32; ++ee) p = fmaf(rp[ee], rp[ee], p);

    const float scale = p / ((1.0f + p) * sqrtf(p + 1e-7f));
    const float o = scale * sum;
    const size_t off = ((size_t)b * NJ + j) * NE + e;
    if (mode == 2)      out[off]  = o;
    else if (mode == 1) Oacc[off] += o;
    else                Oacc[off] = o;
}

extern "C" void kernel_launch(void* const* d_in, const int* in_sizes, int n_in,
                              void* d_out, int out_size, void* d_ws, size_t ws_size,
                              hipStream_t stream)
{
    (void)in_sizes; (void)n_in; (void)out_size; (void)ws_size;
    const float* x = (const float*)d_in[0];   // [64][2048][16]
    const float* W = (const float*)d_in[1];   // [32][2048][32][16]
    float* out = (float*)d_out;               // [64][32][32]

    // ws layout (~104 MB of 512 MB). Every buffer fully written before read.
    float* Oacc = (float*)d_ws;                        // 64K floats  (256 KB)
    float* c    = Oacc + NB * NJ * NE;                 // [NJ][NI][NB] (16 MB)
    float* part = c + (size_t)NJ * NI * NB;            // [NSL][NJ][2048] (16 MB)
    short* Wb   = (short*)(part + (size_t)NSL * NJ * 2048);  // 32M bf16 (64 MB)
    short* xT   = Wb + (size_t)NJ * NIP * NE * 32;           // 4M bf16  (8 MB)

    convxT_k<<<(NI * NB) / 256, 256, 0, stream>>>(x, xT);

    dim3 gW(NJ, NKC);          // wsum grid (32, 64), 128-thread blocks

    // round 0: uniform c = 1/32; converts W -> Wb inline
    wsum_k<true><<<gW, 128, 0, stream>>>(W, xT, Wb, c, part);
    rs_k<<<65536 / 512, 512, 0, stream>>>(part, Oacc, out, 0);

    // round 1
    lgsm_k<<<512, 512, 0, stream>>>(xT, Wb, Oacc, c);
    wsum_k<false><<<gW, 128, 0, stream>>>(W, xT, Wb, c, part);
    rs_k<<<65536 / 512, 512, 0, stream>>>(part, Oacc, out, 1);

    // round 2
    lgsm_k<<<512, 512, 0, stream>>>(xT, Wb, Oacc, c);
    wsum_k<false><<<gW, 128, 0, stream>>>(W, xT, Wb, c, part);
    rs_k<<<65536 / 512, 512, 0, stream>>>(part, Oacc, out, 2);
}

// Round 3
// 339.130 us; speedup vs baseline: 1.2946x; 1.1260x over previous
//
#include <hip/hip_runtime.h>
#include <hip/hip_bf16.h>

#define NB 64     // batch
#define NI 2048   // input capsules
#define ND 16     // d_in
#define NJ 32     // output capsules
#define NE 32     // d_out
#define NIP (NI/2)  // i-pairs
#define NKC 64    // wsum grid kc dimension (64 chunks of 16 ip)
#define NSL NKC   // one partial slice per wsum block (2-wave LDS reduce)

typedef __attribute__((ext_vector_type(8))) short bfrag;   // 8 bf16 (4 VGPRs)
typedef __attribute__((ext_vector_type(4))) float f32x4;

// two floats -> packed bf16x2 (v_cvt_pk_bf16_f32 on gfx950), RNE
__device__ inline unsigned pk2bf(float a, float b) {
    __hip_bfloat162 h = __float22bfloat162_rn(make_float2(a, b));
    return *reinterpret_cast<unsigned*>(&h);
}

// add value rotated by N within each 16-lane DPP row (row_ror:N)
template <int N>
__device__ inline float rot16_add(float v) {
    int r = __builtin_amdgcn_mov_dpp(__float_as_int(v), 0x120 + N, 0xf, 0xf, false);
    return v + __int_as_float(r);
}

// unpack a dword of 2 bf16, scale by cc, repack (RNE)
__device__ inline unsigned scale_pair(unsigned u, float cc) {
    float f0 = __uint_as_float(u << 16);
    float f1 = __uint_as_float(u & 0xffff0000u);
    return pk2bf(f0 * cc, f1 * cc);
}

// ---------------------------------------------------------------------------
// convxT_k: x fp32 [NB][NI][ND] -> xT bf16 [NI][NB][ND].
// ---------------------------------------------------------------------------
__global__ __launch_bounds__(256) void convxT_k(const float* __restrict__ x,
                                                short* __restrict__ xT)
{
    const int T = blockIdx.x * 256 + threadIdx.x;   // NI*NB = 131072
    const int i = T >> 6, b = T & 63;
    const float4* src = reinterpret_cast<const float4*>(
        x + ((size_t)b * NI + i) * ND);
    float4 a0 = src[0], a1 = src[1], a2 = src[2], a3 = src[3];
    bfrag lo, hi;
    unsigned* lu = reinterpret_cast<unsigned*>(&lo);
    unsigned* hu = reinterpret_cast<unsigned*>(&hi);
    lu[0] = pk2bf(a0.x, a0.y); lu[1] = pk2bf(a0.z, a0.w);
    lu[2] = pk2bf(a1.x, a1.y); lu[3] = pk2bf(a1.z, a1.w);
    hu[0] = pk2bf(a2.x, a2.y); hu[1] = pk2bf(a2.z, a2.w);
    hu[2] = pk2bf(a3.x, a3.y); hu[3] = pk2bf(a3.z, a3.w);
    short* dst = xT + ((size_t)i * NB + b) * ND;
    *reinterpret_cast<bfrag*>(dst)     = lo;
    *reinterpret_cast<bfrag*>(dst + 8) = hi;
}

// ---------------------------------------------------------------------------
// lgsm_k: fused logits + softmax (unchanged, proven; ~25us). Flat grid 512
// with XCD co-location swizzle.
// ---------------------------------------------------------------------------
__global__ __launch_bounds__(512) void lgsm_k(
    const short* __restrict__ xT,     // [NI][NB][ND] bf16
    const short* __restrict__ Wb,     // [NJ][NIP][NE][32] bf16
    const float* __restrict__ Oacc,   // [NB][NJ][NE]
    float* __restrict__ c)            // [NJ][NI][NB]
{
    const int l    = blockIdx.x;       // 0..511
    const int grp  = l >> 5;           // 16 groups
    const int bb   = (l >> 3) & 3;
    const int ic   = grp * 8 + (l & 7);
    const int b0   = bb * 16;
    const int i0   = ic * 16;
    const int t    = threadIdx.x;
    const int wv   = t >> 6;           // 0..7 -> j-set wv*4..wv*4+3
    const int ln   = t & 63;
    const int m    = ln & 15;
    const int quad = ln >> 4;

    __shared__ float lp[NJ][16][16];   // [j][i][b] 32 KB

    float O0[4][4], O1[4][4];
#pragma unroll
    for (int jj = 0; jj < 4; ++jj) {
        const int j = wv * 4 + jj;
#pragma unroll
        for (int r = 0; r < 4; ++r) {
            const int b = b0 + quad * 4 + r;
            O0[jj][r] = Oacc[((size_t)b * NJ + j) * NE + m];
            O1[jj][r] = Oacc[((size_t)b * NJ + j) * NE + 16 + m];
        }
    }

    const int  bA  = b0 + m;
    const bool act = quad < 2;
    const int  d0  = quad * 8;

    for (int il = 0; il < 16; ++il) {
        const int i = i0 + il;
        const int ip = i >> 1, isel = i & 1;
        bfrag av = (bfrag)0;
        if (act) {
            av = *reinterpret_cast<const bfrag*>(
                xT + ((size_t)i * NB + bA) * ND + d0);
        }
#pragma unroll
        for (int jj = 0; jj < 4; ++jj) {
            const int j = wv * 4 + jj;
            bfrag bv0 = (bfrag)0, bv1 = (bfrag)0;
            if (act) {
                const short* wp = Wb + (((size_t)j * NIP + ip) * NE + m) * 32
                                     + isel * 16 + d0;
                bv0 = *reinterpret_cast<const bfrag*>(wp);
                bv1 = *reinterpret_cast<const bfrag*>(wp + 16 * 32);
            }
            f32x4 z = {0.f, 0.f, 0.f, 0.f};
            f32x4 U0 = __builtin_amdgcn_mfma_f32_16x16x32_bf16(av, bv0, z, 0, 0, 0);
            f32x4 U1 = __builtin_amdgcn_mfma_f32_16x16x32_bf16(av, bv1, z, 0, 0, 0);

            float v4[4];
#pragma unroll
            for (int r = 0; r < 4; ++r) {
                float v = fmaf(U0[r], O0[jj][r], U1[r] * O1[jj][r]);
                v = rot16_add<1>(v);
                v = rot16_add<2>(v);
                v = rot16_add<4>(v);
                v = rot16_add<8>(v);
                v4[r] = v;
            }
            if (m == 0) {
                *reinterpret_cast<float4*>(&lp[j][il][quad * 4]) =
                    make_float4(v4[0], v4[1], v4[2], v4[3]);
            }
        }
    }
    __syncthreads();

    if (t < 256) {
        const int i = t >> 4, b = t & 15;
        float v[NJ];
        float mx = -1e30f;
#pragma unroll
        for (int jx = 0; jx < NJ; ++jx) {
            v[jx] = lp[jx][i][b];
            mx = fmaxf(mx, v[jx]);
        }
        float sum = 0.f;
#pragma unroll
        for (int jx = 0; jx < NJ; ++jx) {
            v[jx] = __expf(v[jx] - mx);
            sum += v[jx];
        }
        const float inv = 1.0f / sum;
#pragma unroll
        for (int jx = 0; jx < NJ; ++jx)
            c[((size_t)jx * NI + i0 + i) * NB + b0 + b] = v[jx] * inv;
    }
}

// ---------------------------------------------------------------------------
// wsum_k round-3: same per-lane math as the proven kernel, two mechanism
// fixes for the 104us latency wall:
//  (1) NO structs/lambdas/arrays for the 2-deep prefetch pipeline --
//      individually NAMED variables via macros. Round-2's Stage struct went
//      to scratch (VGPR=56, +64MiB phantom WRITE_SIZE = spill signature);
//      named scalars force register residency -> real MLP.
//  (2) XCD-grouped decode: flat grid 2048; x = l&7 selects kc-group x*8..x*8+7
//      so each XCD's resident blocks touch only 8 xT slices (512 KiB, fits
//      4 MiB L2) instead of all 64 (8 MiB, thrash -> every xT read at LLC
//      latency). Same trick that keeps lgsm at ~25us.
// Block = 128 thr (2 waves), all 2048 blocks machine-resident.
// ---------------------------------------------------------------------------

#define WS_LOAD(P, itv)                                                        \
    {   const int ip_ = ip0 + (itv);                                           \
        const int ia_ = ip_ * 2 + isel;                                        \
        if constexpr (R0) {                                                    \
            const float* wp_ = Wsrc + (((size_t)j * NI + ia_) * NE + m) * ND + d0; \
            P##w0 = *reinterpret_cast<const float4*>(wp_);                     \
            P##w1 = *reinterpret_cast<const float4*>(wp_ + 4);                 \
            P##w2 = *reinterpret_cast<const float4*>(wp_ + 16 * ND);           \
            P##w3 = *reinterpret_cast<const float4*>(wp_ + 16 * ND + 4);       \
        } else {                                                               \
            const short* bp_ = Wb + (((size_t)j * NIP + ip_) * NE + m) * 32 + quad * 8; \
            P##bv0 = *reinterpret_cast<const bfrag*>(bp_);                     \
            P##bv1 = *reinterpret_cast<const bfrag*>(bp_ + 512);               \
            const float* cp_ = cbuf + ((size_t)j * NI + ia_) * NB + m;         \
            P##c0 = cp_[0];  P##c1 = cp_[16];                                  \
            P##c2 = cp_[32]; P##c3 = cp_[48];                                  \
        }                                                                      \
        const short* xp_ = xT + ((size_t)ia_ * NB + m) * ND + d0;              \
        P##x0 = *reinterpret_cast<const uint4*>(xp_);                          \
        P##x1 = *reinterpret_cast<const uint4*>(xp_ + 16 * ND);                \
        P##x2 = *reinterpret_cast<const uint4*>(xp_ + 32 * ND);                \
        P##x3 = *reinterpret_cast<const uint4*>(xp_ + 48 * ND);                \
    }

#define WS_MT(XV, CV, A0, A1)                                                  \
    {   const float cc_ = R0 ? (1.0f / NJ) : (CV);                             \
        bfrag av_;                                                             \
        unsigned* au_ = reinterpret_cast<unsigned*>(&av_);                     \
        au_[0] = scale_pair((XV).x, cc_); au_[1] = scale_pair((XV).y, cc_);    \
        au_[2] = scale_pair((XV).z, cc_); au_[3] = scale_pair((XV).w, cc_);    \
        A0 = __builtin_amdgcn_mfma_f32_16x16x32_bf16(av_, bv0_, A0, 0, 0, 0);  \
        A1 = __builtin_amdgcn_mfma_f32_16x16x32_bf16(av_, bv1_, A1, 0, 0, 0);  \
    }

#define WS_COMPUTE(P, itv)                                                     \
    {   bfrag bv0_, bv1_;                                                      \
        if constexpr (R0) {                                                    \
            unsigned* b0_ = reinterpret_cast<unsigned*>(&bv0_);                \
            unsigned* b1_ = reinterpret_cast<unsigned*>(&bv1_);                \
            b0_[0] = pk2bf(P##w0.x, P##w0.y); b0_[1] = pk2bf(P##w0.z, P##w0.w);\
            b0_[2] = pk2bf(P##w1.x, P##w1.y); b0_[3] = pk2bf(P##w1.z, P##w1.w);\
            b1_[0] = pk2bf(P##w2.x, P##w2.y); b1_[1] = pk2bf(P##w2.z, P##w2.w);\
            b1_[2] = pk2bf(P##w3.x, P##w3.y); b1_[3] = pk2bf(P##w3.z, P##w3.w);\
            short* wd_ = Wb + (((size_t)j * NIP + (ip0 + (itv))) * NE + m) * 32 + quad * 8; \
            *reinterpret_cast<bfrag*>(wd_)       = bv0_;                       \
            *reinterpret_cast<bfrag*>(wd_ + 512) = bv1_;                       \
        } else { bv0_ = P##bv0; bv1_ = P##bv1; }                               \
        WS_MT(P##x0, P##c0, a00, a01)                                          \
        WS_MT(P##x1, P##c1, a10, a11)                                          \
        WS_MT(P##x2, P##c2, a20, a21)                                          \
        WS_MT(P##x3, P##c3, a30, a31)                                          \
    }

template <bool R0>
__global__ __launch_bounds__(128, 4) void wsum_k(
    const float* __restrict__ Wsrc,   // [NJ][NI][NE][ND] fp32 (used iff R0)
    const short* __restrict__ xT,     // [NI][NB][ND] bf16
    short* __restrict__ Wb,           // [NJ][NIP][NE][32] bf16 (W iff R0, R else)
    const float* __restrict__ cbuf,   // [NJ][NI][NB] (unused if R0)
    float* __restrict__ partial)      // [NSL][NJ][2048]
{
    const int l    = blockIdx.x;       // 0..2047
    const int x    = l & 7;            // XCD slot (round-robin heuristic)
    const int r    = l >> 3;           // 0..255
    const int j    = r & 31;
    const int kc   = x * 8 + (r >> 5); // XCD-grouped kc: 8 slices per XCD
    const int t    = threadIdx.x;      // 0..127
    const int wv   = t >> 6;           // 0..1
    const int ln   = t & 63;
    const int m    = ln & 15;
    const int quad = ln >> 4;
    const int isel = quad >> 1;        // which of the 2 i's in the K-chunk
    const int d0   = (quad & 1) * 8;   // which 8 d's (element offset)
    const int ip0  = kc * 16 + wv * 8; // this wave's 8 i-pairs

    __shared__ float red[2][2048];     // 16 KB cross-wave reduction buffer

    f32x4 a00 = {0.f,0.f,0.f,0.f}, a01 = {0.f,0.f,0.f,0.f};
    f32x4 a10 = {0.f,0.f,0.f,0.f}, a11 = {0.f,0.f,0.f,0.f};
    f32x4 a20 = {0.f,0.f,0.f,0.f}, a21 = {0.f,0.f,0.f,0.f};
    f32x4 a30 = {0.f,0.f,0.f,0.f}, a31 = {0.f,0.f,0.f,0.f};

    // named 2-deep pipeline state (A set / B set) -- scalars only, no arrays
    bfrag  Abv0, Abv1, Bbv0, Bbv1;
    float4 Aw0, Aw1, Aw2, Aw3, Bw0, Bw1, Bw2, Bw3;
    uint4  Ax0, Ax1, Ax2, Ax3, Bx0, Bx1, Bx2, Bx3;
    float  Ac0, Ac1, Ac2, Ac3, Bc0, Bc1, Bc2, Bc3;

    WS_LOAD(A, 0)
    WS_LOAD(B, 1)
    WS_COMPUTE(A, 0)
    WS_LOAD(A, 2)
    WS_COMPUTE(B, 1)
    WS_LOAD(B, 3)
    WS_COMPUTE(A, 2)
    WS_LOAD(A, 4)
    WS_COMPUTE(B, 3)
    WS_LOAD(B, 5)
    WS_COMPUTE(A, 4)
    WS_LOAD(A, 6)
    WS_COMPUTE(B, 5)
    WS_LOAD(B, 7)
    WS_COMPUTE(A, 6)
    WS_COMPUTE(B, 7)

    // stage per-wave accumulators in the SAME flat layout rs_k decodes
    float* rb = &red[wv][0];
    *reinterpret_cast<f32x4*>(rb + 0 * 256 + ln * 4) = a00;
    *reinterpret_cast<f32x4*>(rb + 1 * 256 + ln * 4) = a01;
    *reinterpret_cast<f32x4*>(rb + 2 * 256 + ln * 4) = a10;
    *reinterpret_cast<f32x4*>(rb + 3 * 256 + ln * 4) = a11;
    *reinterpret_cast<f32x4*>(rb + 4 * 256 + ln * 4) = a20;
    *reinterpret_cast<f32x4*>(rb + 5 * 256 + ln * 4) = a21;
    *reinterpret_cast<f32x4*>(rb + 6 * 256 + ln * 4) = a30;
    *reinterpret_cast<f32x4*>(rb + 7 * 256 + ln * 4) = a31;
    __syncthreads();

    // cooperative 2-wave sum -> one coalesced 8 KB slice per block
    float* pb = partial + ((size_t)kc * NJ + j) * 2048;
#pragma unroll
    for (int k = 0; k < 4; ++k) {
        const int g = k * 512 + t * 4;
        f32x4 s = *reinterpret_cast<const f32x4*>(&red[0][g]);
        s += *reinterpret_cast<const f32x4*>(&red[1][g]);
        *reinterpret_cast<f32x4*>(pb + g) = s;
    }
}

// ---------------------------------------------------------------------------
// rs_k: fused reduce (sum over NSL slices) + squash + state update.
// ---------------------------------------------------------------------------
__global__ __launch_bounds__(512) void rs_k(
    const float* __restrict__ partial,   // [NSL][NJ][2048]
    float* __restrict__ Oacc,            // [NB][NJ][NE]
    float* __restrict__ out,             // [NB][NJ][NE]
    int mode)
{
    const int G    = blockIdx.x * 512 + threadIdx.x;   // 0..65535
    const int j    = G >> 11;
    const int g    = G & 2047;
    const int group = g >> 8;           // 0..7 = mt*2+nt
    const int mt   = group >> 1;
    const int nt   = group & 1;
    const int lnn  = (g >> 2) & 63;
    const int m    = lnn & 15;
    const int quad = lnn >> 4;
    const int r    = g & 3;
    const int b    = mt * 16 + quad * 4 + r;
    const int e    = nt * 16 + m;

    float sum = 0.f;
#pragma unroll 8
    for (int sl = 0; sl < NSL; ++sl)
        sum += partial[((size_t)sl * NJ + j) * 2048 + g];

    __shared__ float lds[512];
    const int row = quad * 4 + r;        // 0..15
    lds[row * 32 + e] = sum;
    __syncthreads();
    const float* rp = &lds[row * 32];
    float p = 0.f;
#pragma unroll
    for (int ee = 0; ee < 32; ++ee) p = fmaf(rp[ee], rp[ee], p);

    const float scale = p / ((1.0f + p) * sqrtf(p + 1e-7f));
    const float o = scale * sum;
    const size_t off = ((size_t)b * NJ + j) * NE + e;
    if (mode == 2)      out[off]  = o;
    else if (mode == 1) Oacc[off] += o;
    else                Oacc[off] = o;
}

extern "C" void kernel_launch(void* const* d_in, const int* in_sizes, int n_in,
                              void* d_out, int out_size, void* d_ws, size_t ws_size,
                              hipStream_t stream)
{
    (void)in_sizes; (void)n_in; (void)out_size; (void)ws_size;
    const float* x = (const float*)d_in[0];   // [64][2048][16]
    const float* W = (const float*)d_in[1];   // [32][2048][32][16]
    float* out = (float*)d_out;               // [64][32][32]

    // ws layout (~104 MB of 512 MB). Every buffer fully written before read.
    float* Oacc = (float*)d_ws;                        // 64K floats  (256 KB)
    float* c    = Oacc + NB * NJ * NE;                 // [NJ][NI][NB] (16 MB)
    float* part = c + (size_t)NJ * NI * NB;            // [NSL][NJ][2048] (16 MB)
    short* Wb   = (short*)(part + (size_t)NSL * NJ * 2048);  // 32M bf16 (64 MB)
    short* xT   = Wb + (size_t)NJ * NIP * NE * 32;           // 4M bf16  (8 MB)

    convxT_k<<<(NI * NB) / 256, 256, 0, stream>>>(x, xT);

    // round 0: uniform c = 1/32; converts W -> Wb inline
    wsum_k<true><<<NJ * NKC, 128, 0, stream>>>(W, xT, Wb, c, part);
    rs_k<<<65536 / 512, 512, 0, stream>>>(part, Oacc, out, 0);

    // round 1
    lgsm_k<<<512, 512, 0, stream>>>(xT, Wb, Oacc, c);
    wsum_k<false><<<NJ * NKC, 128, 0, stream>>>(W, xT, Wb, c, part);
    rs_k<<<65536 / 512, 512, 0, stream>>>(part, Oacc, out, 1);

    // round 2
    lgsm_k<<<512, 512, 0, stream>>>(xT, Wb, Oacc, c);
    wsum_k<false><<<NJ * NKC, 128, 0, stream>>>(W, xT, Wb, c, part);
    rs_k<<<65536 / 512, 512, 0, stream>>>(part, Oacc, out, 2);
}